// Round 3
// baseline (1032.110 us; speedup 1.0000x reference)
//
#include <hip/hip_runtime.h>
#include <stdint.h>
#include <stddef.h>

typedef unsigned short u16;
typedef __bf16 bf16x8 __attribute__((ext_vector_type(8)));
typedef float f32x4 __attribute__((ext_vector_type(4)));

#define DEVINL __device__ __forceinline__

DEVINL u16 f2bf(float f) {
  uint32_t u = __builtin_bit_cast(uint32_t, f);
  u += 0x7FFFu + ((u >> 16) & 1u);   // RNE (finite values only here)
  return (u16)(u >> 16);
}
DEVINL float bf2f(u16 h) {
  uint32_t u = ((uint32_t)h) << 16;
  return __builtin_bit_cast(float, u);
}
DEVINL uint32_t pack2(float a, float b) {
  return (uint32_t)f2bf(a) | ((uint32_t)f2bf(b) << 16);
}

DEVINL void gload_lds16(const u16* g, u16* lds) {
  __builtin_amdgcn_global_load_lds(
      (const __attribute__((address_space(1))) uint32_t*)g,
      (__attribute__((address_space(3))) uint32_t*)lds, 16, 0, 0);
}

// ---------------- cast f32 -> bf16, 8 elem/thread ----------------
__global__ __launch_bounds__(256) void cast_kernel(const float* __restrict__ x,
                                                   u16* __restrict__ y, int n8) {
  int i = blockIdx.x * 256 + threadIdx.x;
  if (i >= n8) return;
  const float4* xp = (const float4*)x + (size_t)i * 2;
  float4 a = xp[0], b = xp[1];
  uint4 o;
  o.x = pack2(a.x, a.y);
  o.y = pack2(a.z, a.w);
  o.z = pack2(b.x, b.y);
  o.w = pack2(b.z, b.w);
  ((uint4*)y)[i] = o;
}

// ------------- transpose + cast: Bt[n][k] = W[k][n] (bf16) -------------
// grid: (N/64, K/64), 256 threads
__global__ __launch_bounds__(256) void transpose_cast(const float* __restrict__ W,
                                                      u16* __restrict__ Bt,
                                                      int K, int N) {
  __shared__ float tile[64][65];
  const int nb = blockIdx.x << 6, kb = blockIdx.y << 6;
  const int t = threadIdx.x;
  {
    const int kr = t >> 2, n0 = (t & 3) << 4;
    const float* src = W + (size_t)(kb + kr) * N + nb + n0;
#pragma unroll
    for (int i = 0; i < 16; i += 4) {
      float4 v = *(const float4*)(src + i);
      tile[n0 + i + 0][kr] = v.x;
      tile[n0 + i + 1][kr] = v.y;
      tile[n0 + i + 2][kr] = v.z;
      tile[n0 + i + 3][kr] = v.w;
    }
  }
  __syncthreads();
  {
    const int nr = t >> 2, k0 = (t & 3) << 4;
    u16* dst = Bt + (size_t)(nb + nr) * K + kb + k0;
#pragma unroll
    for (int i = 0; i < 16; i += 8) {
      uint4 o;
      o.x = pack2(tile[nr][k0 + i + 0], tile[nr][k0 + i + 1]);
      o.y = pack2(tile[nr][k0 + i + 2], tile[nr][k0 + i + 3]);
      o.z = pack2(tile[nr][k0 + i + 4], tile[nr][k0 + i + 5]);
      o.w = pack2(tile[nr][k0 + i + 6], tile[nr][k0 + i + 7]);
      *(uint4*)(dst + i) = o;
    }
  }
}

// ------------- bf16 MFMA GEMM: C[M][N] = A[M][K] * Bt[N][K]^T + bias -------------
// m97-style structure: BK=32, 256 threads (4 waves), global_load_lds staging.
template <int BM, int BN, int WM, int WN, bool OUTF32>
__global__ __launch_bounds__(256) void gemm_bf16t(const u16* __restrict__ A,
                                                  const u16* __restrict__ Bt,
                                                  const float* __restrict__ bias,
                                                  void* __restrict__ Cv,
                                                  int M, int N, int K) {
  static_assert(WM * WN == 4, "4 waves");
  constexpr int BK = 32;
  constexpr int FM = BM / (WM * 16);
  constexpr int FN = BN / (WN * 16);
  __shared__ __align__(16) u16 Al[BM * BK];
  __shared__ __align__(16) u16 Bl[BN * BK];
  const int t = threadIdx.x;
  const int lane = t & 63, w = t >> 6;
  const int wm = w / WN, wn = w % WN;
  const int bm = blockIdx.y * BM, bn = blockIdx.x * BN;
  const int r16 = lane & 15, khi = lane >> 4;

  f32x4 acc[FM][FN] = {};

  const int srow = t >> 2;           // staging row within a 64-row round
  const int skel = (t & 3) << 3;     // staging k-offset (elements)

  for (int k0 = 0; k0 < K; k0 += BK) {
#pragma unroll
    for (int r = 0; r < BM / 64; ++r) {
      const u16* g = A + (size_t)(bm + r * 64 + srow) * K + k0 + skel;
      gload_lds16(g, Al + r * 2048 + (w << 9));
    }
#pragma unroll
    for (int r = 0; r < BN / 64; ++r) {
      const u16* g = Bt + (size_t)(bn + r * 64 + srow) * K + k0 + skel;
      gload_lds16(g, Bl + r * 2048 + (w << 9));
    }
    __syncthreads();

    bf16x8 af[FM], bfr[FN];
#pragma unroll
    for (int mi = 0; mi < FM; ++mi)
      af[mi] = *(const bf16x8*)(Al + (wm * FM * 16 + mi * 16 + r16) * BK + khi * 8);
#pragma unroll
    for (int ni = 0; ni < FN; ++ni)
      bfr[ni] = *(const bf16x8*)(Bl + (wn * FN * 16 + ni * 16 + r16) * BK + khi * 8);
#pragma unroll
    for (int mi = 0; mi < FM; ++mi)
#pragma unroll
      for (int ni = 0; ni < FN; ++ni)
        acc[mi][ni] = __builtin_amdgcn_mfma_f32_16x16x32_bf16(af[mi], bfr[ni],
                                                              acc[mi][ni], 0, 0, 0);
    __syncthreads();
  }

  // epilogue: C/D layout col = lane&15, row = (lane>>4)*4 + e  [m89/m91-verified]
  const int crow0 = bm + wm * FM * 16 + (khi << 2);
  const int ccol0 = bn + wn * FN * 16 + r16;
#pragma unroll
  for (int mi = 0; mi < FM; ++mi) {
#pragma unroll
    for (int ni = 0; ni < FN; ++ni) {
      const int col = ccol0 + ni * 16;
      const float bv = bias ? bias[col] : 0.0f;
#pragma unroll
      for (int e = 0; e < 4; ++e) {
        const int row = crow0 + mi * 16 + e;
        const float v = acc[mi][ni][e] + bv;
        if (OUTF32)
          ((float*)Cv)[(size_t)row * N + col] = v;
        else
          ((u16*)Cv)[(size_t)row * N + col] = f2bf(v);
      }
    }
  }
}

// ------------- fused per-token attention -------------
// qT[c][m] = q[s][m][c]; k[j][m]; v[j][m]; logits[c][j] = sum_m qT[c][m]*k[j][m]
// attn = log_softmax_rows(logits) * keep;  out[i][j] = sum_m attn[i][m]*v[j][m]
__global__ __launch_bounds__(256) void attn_kernel(const u16* __restrict__ Q,
                                                   const u16* __restrict__ Kp,
                                                   const u16* __restrict__ Vp,
                                                   const float* __restrict__ mask,
                                                   u16* __restrict__ OUT) {
  constexpr int LD = 66;
  __shared__ float qT[64 * LD];
  __shared__ float kl[64 * LD];
  __shared__ float vl[64 * LD];
  __shared__ float sc[64 * LD];
  const int s = blockIdx.x;
  const int t = threadIdx.x;
  const size_t base = (size_t)s << 12;  // * 4096

  // ---- stage q (transposed), k, v into LDS as f32 ----
  {
    float v0[8], v1[8];
    const int rr = t >> 2, c0 = (t & 3) << 4;

    const uint4* qp = (const uint4*)(Q + base) + (t << 1);
    uint4 a = qp[0], b = qp[1];
#pragma unroll
    for (int i = 0; i < 4; ++i) {
      uint32_t wlo = ((const uint32_t*)&a)[i];
      v0[2 * i] = bf2f((u16)(wlo & 0xffffu));
      v0[2 * i + 1] = bf2f((u16)(wlo >> 16));
      uint32_t whi = ((const uint32_t*)&b)[i];
      v1[2 * i] = bf2f((u16)(whi & 0xffffu));
      v1[2 * i + 1] = bf2f((u16)(whi >> 16));
    }
#pragma unroll
    for (int i = 0; i < 8; ++i) qT[(c0 + i) * LD + rr] = v0[i];
#pragma unroll
    for (int i = 0; i < 8; ++i) qT[(c0 + 8 + i) * LD + rr] = v1[i];

    const uint4* kp = (const uint4*)(Kp + base) + (t << 1);
    a = kp[0]; b = kp[1];
#pragma unroll
    for (int i = 0; i < 4; ++i) {
      uint32_t wlo = ((const uint32_t*)&a)[i];
      kl[rr * LD + c0 + 2 * i] = bf2f((u16)(wlo & 0xffffu));
      kl[rr * LD + c0 + 2 * i + 1] = bf2f((u16)(wlo >> 16));
      uint32_t whi = ((const uint32_t*)&b)[i];
      kl[rr * LD + c0 + 8 + 2 * i] = bf2f((u16)(whi & 0xffffu));
      kl[rr * LD + c0 + 8 + 2 * i + 1] = bf2f((u16)(whi >> 16));
    }
    const uint4* vp = (const uint4*)(Vp + base) + (t << 1);
    a = vp[0]; b = vp[1];
#pragma unroll
    for (int i = 0; i < 4; ++i) {
      uint32_t wlo = ((const uint32_t*)&a)[i];
      vl[rr * LD + c0 + 2 * i] = bf2f((u16)(wlo & 0xffffu));
      vl[rr * LD + c0 + 2 * i + 1] = bf2f((u16)(wlo >> 16));
      uint32_t whi = ((const uint32_t*)&b)[i];
      vl[rr * LD + c0 + 8 + 2 * i] = bf2f((u16)(whi & 0xffffu));
      vl[rr * LD + c0 + 8 + 2 * i + 1] = bf2f((u16)(whi >> 16));
    }
  }
  __syncthreads();

  const int c0 = (t >> 4) << 2;
  const int j0 = (t & 15) << 2;

  // ---- phase B: logits ----
  {
    float a4[4][4] = {};
#pragma unroll 4
    for (int mc = 0; mc < 64; mc += 2) {
      float2 qv[4], kv[4];
#pragma unroll
      for (int i = 0; i < 4; ++i) {
        qv[i] = *(const float2*)&qT[(c0 + i) * LD + mc];
        kv[i] = *(const float2*)&kl[(j0 + i) * LD + mc];
      }
#pragma unroll
      for (int i = 0; i < 4; ++i)
#pragma unroll
        for (int j = 0; j < 4; ++j)
          a4[i][j] += qv[i].x * kv[j].x + qv[i].y * kv[j].y;
    }
#pragma unroll
    for (int i = 0; i < 4; ++i)
#pragma unroll
      for (int j = 0; j < 4; ++j) sc[(c0 + i) * LD + j0 + j] = a4[i][j];
  }
  __syncthreads();

  // ---- phase C: log_softmax over rows + dropout mask ----
  {
    const int rc = t >> 2;
    const int q0 = (t & 3) << 4;
    float x[16];
#pragma unroll
    for (int i = 0; i < 16; ++i) x[i] = sc[rc * LD + q0 + i];
    float mx = x[0];
#pragma unroll
    for (int i = 1; i < 16; ++i) mx = fmaxf(mx, x[i]);
    mx = fmaxf(mx, __shfl_xor(mx, 1));
    mx = fmaxf(mx, __shfl_xor(mx, 2));
    float sm = 0.0f;
#pragma unroll
    for (int i = 0; i < 16; ++i) sm += __expf(x[i] - mx);
    sm += __shfl_xor(sm, 1);
    sm += __shfl_xor(sm, 2);
    const float L = mx + __logf(sm);
    const float4* mp = (const float4*)(mask + base + (size_t)rc * 64 + q0);
#pragma unroll
    for (int i4 = 0; i4 < 4; ++i4) {
      float4 mv = mp[i4];
      sc[rc * LD + q0 + i4 * 4 + 0] =
          (x[i4 * 4 + 0] - L) * (mv.x > 0.25f ? (1.0f / 0.75f) : 0.0f);
      sc[rc * LD + q0 + i4 * 4 + 1] =
          (x[i4 * 4 + 1] - L) * (mv.y > 0.25f ? (1.0f / 0.75f) : 0.0f);
      sc[rc * LD + q0 + i4 * 4 + 2] =
          (x[i4 * 4 + 2] - L) * (mv.z > 0.25f ? (1.0f / 0.75f) : 0.0f);
      sc[rc * LD + q0 + i4 * 4 + 3] =
          (x[i4 * 4 + 3] - L) * (mv.w > 0.25f ? (1.0f / 0.75f) : 0.0f);
    }
  }
  __syncthreads();

  // ---- phase D: out = attn @ vT ----
  {
    float b4[4][4] = {};
#pragma unroll 4
    for (int mc = 0; mc < 64; mc += 2) {
      float2 av[4], vv[4];
#pragma unroll
      for (int i = 0; i < 4; ++i) {
        av[i] = *(const float2*)&sc[(c0 + i) * LD + mc];
        vv[i] = *(const float2*)&vl[(j0 + i) * LD + mc];
      }
#pragma unroll
      for (int i = 0; i < 4; ++i)
#pragma unroll
        for (int j = 0; j < 4; ++j)
          b4[i][j] += av[i].x * vv[j].x + av[i].y * vv[j].y;
    }
#pragma unroll
    for (int i = 0; i < 4; ++i)
#pragma unroll
      for (int j = 0; j < 4; ++j)
        OUT[base + (size_t)(c0 + i) * 64 + j0 + j] = f2bf(b4[i][j]);
  }
}

// ---------------- launch ----------------
extern "C" void kernel_launch(void* const* d_in, const int* in_sizes, int n_in,
                              void* d_out, int out_size, void* d_ws, size_t ws_size,
                              hipStream_t stream) {
  (void)in_sizes; (void)n_in; (void)out_size; (void)ws_size;
  const float* query  = (const float*)d_in[0];
  const float* key_in = (const float*)d_in[1];
  const float* value  = (const float*)d_in[2];
  const float* mask_u = (const float*)d_in[3];
  const float* Wq = (const float*)d_in[4];
  const float* bq = (const float*)d_in[5];
  const float* Wk = (const float*)d_in[6];
  const float* bk = (const float*)d_in[7];
  const float* Wv = (const float*)d_in[8];
  const float* bv = (const float*)d_in[9];
  const float* Wo = (const float*)d_in[10];
  const float* bo = (const float*)d_in[11];

  char* ws = (char*)d_ws;
  u16* q_bf   = (u16*)(ws + 0);                              // 64MB
  u16* WqT    = (u16*)(ws + ((size_t)64 << 20));             // 32MB
  u16* key_bf = (u16*)(ws + ((size_t)96 << 20));             // 1MB
  u16* val_bf = (u16*)(ws + ((size_t)97 << 20));             // 1MB
  u16* WkT    = (u16*)(ws + ((size_t)98 << 20));             // 0.5MB
  u16* WvT    = (u16*)(ws + ((size_t)98 << 20) + (512 << 10));
  u16* WoT    = (u16*)(ws + ((size_t)99 << 20));             // 0.5MB
  u16* Qp     = (u16*)(ws + ((size_t)100 << 20));            // 64MB
  u16* Kp     = (u16*)(ws + ((size_t)164 << 20));            // 64MB
  u16* Vp     = (u16*)(ws + ((size_t)228 << 20));            // 64MB
  u16* OUTb   = q_bf;  // alias: q_bf dead after Q-proj GEMM

  // casts
  cast_kernel<<<16384, 256, 0, stream>>>(query, q_bf, 8192 * 4096 / 8);
  cast_kernel<<<256, 256, 0, stream>>>(key_in, key_bf, 8192 * 64 / 8);
  cast_kernel<<<256, 256, 0, stream>>>(value, val_bf, 8192 * 64 / 8);
  // B^T panels
  transpose_cast<<<dim3(64, 64), 256, 0, stream>>>(Wq, WqT, 4096, 4096);
  transpose_cast<<<dim3(64, 1), 256, 0, stream>>>(Wk, WkT, 64, 4096);
  transpose_cast<<<dim3(64, 1), 256, 0, stream>>>(Wv, WvT, 64, 4096);
  transpose_cast<<<dim3(1, 64), 256, 0, stream>>>(Wo, WoT, 4096, 64);

  // projections
  gemm_bf16t<128, 128, 2, 2, false>
      <<<dim3(32, 64), 256, 0, stream>>>(q_bf, WqT, bq, Qp, 8192, 4096, 4096);
  gemm_bf16t<128, 128, 2, 2, false>
      <<<dim3(32, 64), 256, 0, stream>>>(key_bf, WkT, bk, Kp, 8192, 4096, 64);
  gemm_bf16t<128, 128, 2, 2, false>
      <<<dim3(32, 64), 256, 0, stream>>>(val_bf, WvT, bv, Vp, 8192, 4096, 64);

  // fused per-token attention (logits -> log_softmax -> dropout -> @ vT)
  attn_kernel<<<8192, 256, 0, stream>>>(Qp, Kp, Vp, mask_u, OUTb);

  // final projection -> d_out (f32)
  gemm_bf16t<128, 64, 4, 1, true>
      <<<dim3(1, 64), 256, 0, stream>>>(OUTb, WoT, bo, (float*)d_out, 8192, 64, 4096);
}

// Round 4
// 865.629 us; speedup vs baseline: 1.1923x; 1.1923x over previous
//
#include <hip/hip_runtime.h>
#include <stdint.h>
#include <stddef.h>

typedef unsigned short u16;
typedef __bf16 bf16x8 __attribute__((ext_vector_type(8)));
typedef float f32x4 __attribute__((ext_vector_type(4)));

#define DEVINL __device__ __forceinline__

DEVINL u16 f2bf(float f) {
  uint32_t u = __builtin_bit_cast(uint32_t, f);
  u += 0x7FFFu + ((u >> 16) & 1u);   // RNE (finite values only here)
  return (u16)(u >> 16);
}
DEVINL float bf2f(u16 h) {
  uint32_t u = ((uint32_t)h) << 16;
  return __builtin_bit_cast(float, u);
}
DEVINL uint32_t pack2(float a, float b) {
  return (uint32_t)f2bf(a) | ((uint32_t)f2bf(b) << 16);
}

DEVINL void gload_lds16(const u16* g, u16* lds) {
  __builtin_amdgcn_global_load_lds(
      (const __attribute__((address_space(1))) uint32_t*)g,
      (__attribute__((address_space(3))) uint32_t*)lds, 16, 0, 0);
}

// ---------------- cast f32 -> bf16, 8 elem/thread ----------------
__global__ __launch_bounds__(256) void cast_kernel(const float* __restrict__ x,
                                                   u16* __restrict__ y, int n8) {
  int i = blockIdx.x * 256 + threadIdx.x;
  if (i >= n8) return;
  const float4* xp = (const float4*)x + (size_t)i * 2;
  float4 a = xp[0], b = xp[1];
  uint4 o;
  o.x = pack2(a.x, a.y);
  o.y = pack2(a.z, a.w);
  o.z = pack2(b.x, b.y);
  o.w = pack2(b.z, b.w);
  ((uint4*)y)[i] = o;
}

// ------------- transpose + cast: Bt[n][k] = W[k][n] (bf16) -------------
__global__ __launch_bounds__(256) void transpose_cast(const float* __restrict__ W,
                                                      u16* __restrict__ Bt,
                                                      int K, int N) {
  __shared__ float tile[64][65];
  const int nb = blockIdx.x << 6, kb = blockIdx.y << 6;
  const int t = threadIdx.x;
  {
    const int kr = t >> 2, n0 = (t & 3) << 4;
    const float* src = W + (size_t)(kb + kr) * N + nb + n0;
#pragma unroll
    for (int i = 0; i < 16; i += 4) {
      float4 v = *(const float4*)(src + i);
      tile[n0 + i + 0][kr] = v.x;
      tile[n0 + i + 1][kr] = v.y;
      tile[n0 + i + 2][kr] = v.z;
      tile[n0 + i + 3][kr] = v.w;
    }
  }
  __syncthreads();
  {
    const int nr = t >> 2, k0 = (t & 3) << 4;
    u16* dst = Bt + (size_t)(nb + nr) * K + kb + k0;
#pragma unroll
    for (int i = 0; i < 16; i += 8) {
      uint4 o;
      o.x = pack2(tile[nr][k0 + i + 0], tile[nr][k0 + i + 1]);
      o.y = pack2(tile[nr][k0 + i + 2], tile[nr][k0 + i + 3]);
      o.z = pack2(tile[nr][k0 + i + 4], tile[nr][k0 + i + 5]);
      o.w = pack2(tile[nr][k0 + i + 6], tile[nr][k0 + i + 7]);
      *(uint4*)(dst + i) = o;
    }
  }
}

// ------------- bf16 MFMA GEMM: C[M][N] = A[M][K] * Bt[N][K]^T + bias -------------
// m97 structure + XCD-aware bijective swizzle (requires nwg%8==0, else identity).
// SPLITK: blockIdx.x = K-chunk index; A/Bt advanced by chunk*K (elements along k);
//         Cv = f32 partials, chunk-strided by M*N.
template <int BM, int BN, int WM, int WN, bool OUTF32, bool SPLITK>
__global__ __launch_bounds__(256) void gemm_bf16t(const u16* __restrict__ A,
                                                  const u16* __restrict__ Bt,
                                                  const float* __restrict__ bias,
                                                  void* __restrict__ Cv,
                                                  int M, int N, int K,
                                                  int lda, int ldb) {
  static_assert(WM * WN == 4, "4 waves");
  constexpr int BK = 32;
  constexpr int FM = BM / (WM * 16);
  constexpr int FN = BN / (WN * 16);
  __shared__ __align__(16) u16 Al[BM * BK];
  __shared__ __align__(16) u16 Bl[BN * BK];
  const int t = threadIdx.x;
  const int lane = t & 63, w = t >> 6;
  const int wm = w / WN, wn = w % WN;

  // XCD-aware swizzle (bijective when nwg%8==0)
  int bx, by;
  {
    const int nwg = gridDim.x * gridDim.y;
    int bid = blockIdx.y * gridDim.x + blockIdx.x;
    if ((nwg & 7) == 0) {
      const int cpx = nwg >> 3;
      bid = (bid & 7) * cpx + (bid >> 3);
    }
    bx = bid % gridDim.x;
    by = bid / gridDim.x;
  }

  int bn;
  float* Cpart = nullptr;
  if (SPLITK) {
    const int chunk = bx;
    A  += (size_t)chunk * K;      // k-offset within row
    Bt += (size_t)chunk * K;
    Cpart = (float*)Cv + (size_t)chunk * M * N;
    bn = 0;
  } else {
    bn = bx * BN;
  }
  const int bm = by * BM;
  const int r16 = lane & 15, khi = lane >> 4;

  f32x4 acc[FM][FN] = {};

  const int srow = t >> 2;           // staging row within a 64-row round
  const int skel = (t & 3) << 3;     // staging k-offset (elements)

  for (int k0 = 0; k0 < K; k0 += BK) {
#pragma unroll
    for (int r = 0; r < BM / 64; ++r) {
      const u16* g = A + (size_t)(bm + r * 64 + srow) * lda + k0 + skel;
      gload_lds16(g, Al + r * 2048 + (w << 9));
    }
#pragma unroll
    for (int r = 0; r < BN / 64; ++r) {
      const u16* g = Bt + (size_t)(bn + r * 64 + srow) * ldb + k0 + skel;
      gload_lds16(g, Bl + r * 2048 + (w << 9));
    }
    __syncthreads();

    bf16x8 af[FM], bfr[FN];
#pragma unroll
    for (int mi = 0; mi < FM; ++mi)
      af[mi] = *(const bf16x8*)(Al + (wm * FM * 16 + mi * 16 + r16) * BK + khi * 8);
#pragma unroll
    for (int ni = 0; ni < FN; ++ni)
      bfr[ni] = *(const bf16x8*)(Bl + (wn * FN * 16 + ni * 16 + r16) * BK + khi * 8);
#pragma unroll
    for (int mi = 0; mi < FM; ++mi)
#pragma unroll
      for (int ni = 0; ni < FN; ++ni)
        acc[mi][ni] = __builtin_amdgcn_mfma_f32_16x16x32_bf16(af[mi], bfr[ni],
                                                              acc[mi][ni], 0, 0, 0);
    __syncthreads();
  }

  // epilogue: C/D layout col = lane&15, row = (lane>>4)*4 + e  [HW-verified r3]
  const int crow0 = bm + wm * FM * 16 + (khi << 2);
  const int ccol0 = bn + wn * FN * 16 + r16;
#pragma unroll
  for (int mi = 0; mi < FM; ++mi) {
#pragma unroll
    for (int ni = 0; ni < FN; ++ni) {
      const int col = ccol0 + ni * 16;
      const float bv = (!SPLITK && bias) ? bias[col] : 0.0f;
#pragma unroll
      for (int e = 0; e < 4; ++e) {
        const int row = crow0 + mi * 16 + e;
        const float v = acc[mi][ni][e] + bv;
        if (SPLITK)
          Cpart[(size_t)row * N + col] = v;
        else if (OUTF32)
          ((float*)Cv)[(size_t)row * N + col] = v;
        else
          ((u16*)Cv)[(size_t)row * N + col] = f2bf(v);
      }
    }
  }
}

// ------------- split-K reduce: out[i] = sum_c part[c][i] + bias[i%64] -------------
__global__ __launch_bounds__(256) void reduce_splitk(const float* __restrict__ part,
                                                     const float* __restrict__ bo,
                                                     float* __restrict__ out, int n) {
  int i = blockIdx.x * 256 + threadIdx.x;
  if (i >= n) return;
  float s = 0.0f;
#pragma unroll
  for (int c = 0; c < 8; ++c) s += part[(size_t)c * 524288 + i];
  out[i] = s + bo[i & 63];
}

// ------------- MFMA per-token attention -------------
// 1 wave/token, 4 tokens/block, no inter-wave deps (no barriers).
// logits[c][j] = sum_m Qp[s][m*64+c] * Kp[s][j*64+m]   (A=qT staged in LDS, Bt=Kp rows direct)
// attn = log_softmax_rows(logits) * keep;  out[c][jo] = sum_m P[c][m] * Vp[s][jo*64+m]
__global__ __launch_bounds__(256) void attn_mfma(const u16* __restrict__ Q,
                                                 const u16* __restrict__ Kp,
                                                 const u16* __restrict__ Vp,
                                                 const float* __restrict__ mask,
                                                 u16* __restrict__ OUT) {
  constexpr int LDP = 72;  // u16 row stride (144B, 16B-aligned rows)
  __shared__ __align__(16) u16 Pbuf[4][64 * LDP];  // 36864 B
  const int t = threadIdx.x;
  const int w = t >> 6, lane = t & 63;
  const int r16 = lane & 15, khi = lane >> 4;
  const int s = blockIdx.x * 4 + w;
  const size_t base = (size_t)s << 12;  // * 4096
  u16* pb = Pbuf[w];

  // ---- stage qT: lane loads Qp[s] row m=lane (128B), scatters transposed ----
  {
    uint4 rowv[8];
    const uint4* qp = (const uint4*)(Q + base + (size_t)lane * 64);
#pragma unroll
    for (int i = 0; i < 8; ++i) rowv[i] = qp[i];
#pragma unroll
    for (int i = 0; i < 8; ++i) {
      const uint32_t* wp = (const uint32_t*)&rowv[i];
#pragma unroll
      for (int h = 0; h < 4; ++h) {
        uint32_t v = wp[h];
        pb[(8 * i + 2 * h) * LDP + lane] = (u16)(v & 0xffffu);
        pb[(8 * i + 2 * h + 1) * LDP + lane] = (u16)(v >> 16);
      }
    }
  }
  asm volatile("s_waitcnt lgkmcnt(0)" ::: "memory");  // cross-lane LDS RAW fence

  // ---- QK^T via MFMA: acc[mi][ni][e] = logits[16mi+4khi+e][16ni+r16] ----
  f32x4 acc[4][4] = {};
#pragma unroll
  for (int ks = 0; ks < 2; ++ks) {
    bf16x8 af[4], bfr[4];
#pragma unroll
    for (int mi = 0; mi < 4; ++mi)
      af[mi] = *(const bf16x8*)(pb + (16 * mi + r16) * LDP + ks * 32 + khi * 8);
#pragma unroll
    for (int ni = 0; ni < 4; ++ni)
      bfr[ni] = *(const bf16x8*)(Kp + base + (size_t)(16 * ni + r16) * 64 +
                                 ks * 32 + khi * 8);
#pragma unroll
    for (int mi = 0; mi < 4; ++mi)
#pragma unroll
      for (int ni = 0; ni < 4; ++ni)
        acc[mi][ni] = __builtin_amdgcn_mfma_f32_16x16x32_bf16(af[mi], bfr[ni],
                                                              acc[mi][ni], 0, 0, 0);
  }

  // ---- log-softmax over j (cols): reduce over ni (regs) + r16 (shfl_xor 1,2,4,8) ----
  float L[4][4];  // [mi][e]
#pragma unroll
  for (int mi = 0; mi < 4; ++mi) {
#pragma unroll
    for (int e = 0; e < 4; ++e) {
      float mx = fmaxf(fmaxf(acc[mi][0][e], acc[mi][1][e]),
                       fmaxf(acc[mi][2][e], acc[mi][3][e]));
      mx = fmaxf(mx, __shfl_xor(mx, 1));
      mx = fmaxf(mx, __shfl_xor(mx, 2));
      mx = fmaxf(mx, __shfl_xor(mx, 4));
      mx = fmaxf(mx, __shfl_xor(mx, 8));
      float sm = __expf(acc[mi][0][e] - mx) + __expf(acc[mi][1][e] - mx) +
                 __expf(acc[mi][2][e] - mx) + __expf(acc[mi][3][e] - mx);
      sm += __shfl_xor(sm, 1);
      sm += __shfl_xor(sm, 2);
      sm += __shfl_xor(sm, 4);
      sm += __shfl_xor(sm, 8);
      L[mi][e] = mx + __logf(sm);
    }
  }

  // ---- P = (logits - L) * keep  -> bf16 into pb (qT dead; same-wave in-order DS) ----
  const float* mrow = mask + base;
#pragma unroll
  for (int mi = 0; mi < 4; ++mi) {
#pragma unroll
    for (int ni = 0; ni < 4; ++ni) {
#pragma unroll
      for (int e = 0; e < 4; ++e) {
        const int c = 16 * mi + 4 * khi + e;
        const int j = 16 * ni + r16;
        const float keep = mrow[(size_t)c * 64 + j] > 0.25f ? (1.0f / 0.75f) : 0.0f;
        pb[c * LDP + j] = f2bf((acc[mi][ni][e] - L[mi][e]) * keep);
      }
    }
  }
  asm volatile("s_waitcnt lgkmcnt(0)" ::: "memory");  // cross-lane LDS RAW fence

  // ---- PV via MFMA: o[mi][ni][e] = out[16mi+4khi+e][16ni+r16] ----
  f32x4 o[4][4] = {};
#pragma unroll
  for (int ks = 0; ks < 2; ++ks) {
    bf16x8 af[4], bfr[4];
#pragma unroll
    for (int mi = 0; mi < 4; ++mi)
      af[mi] = *(const bf16x8*)(pb + (16 * mi + r16) * LDP + ks * 32 + khi * 8);
#pragma unroll
    for (int ni = 0; ni < 4; ++ni)
      bfr[ni] = *(const bf16x8*)(Vp + base + (size_t)(16 * ni + r16) * 64 +
                                 ks * 32 + khi * 8);
#pragma unroll
    for (int mi = 0; mi < 4; ++mi)
#pragma unroll
      for (int ni = 0; ni < 4; ++ni)
        o[mi][ni] = __builtin_amdgcn_mfma_f32_16x16x32_bf16(af[mi], bfr[ni],
                                                            o[mi][ni], 0, 0, 0);
  }

  // ---- store OUT[s][c*64+jo] bf16 ----
#pragma unroll
  for (int mi = 0; mi < 4; ++mi) {
#pragma unroll
    for (int ni = 0; ni < 4; ++ni) {
#pragma unroll
      for (int e = 0; e < 4; ++e) {
        const int c = 16 * mi + 4 * khi + e;
        const int jo = 16 * ni + r16;
        OUT[base + (size_t)c * 64 + jo] = f2bf(o[mi][ni][e]);
      }
    }
  }
}

// ---------------- launch ----------------
extern "C" void kernel_launch(void* const* d_in, const int* in_sizes, int n_in,
                              void* d_out, int out_size, void* d_ws, size_t ws_size,
                              hipStream_t stream) {
  (void)in_sizes; (void)n_in; (void)out_size; (void)ws_size;
  const float* query  = (const float*)d_in[0];
  const float* key_in = (const float*)d_in[1];
  const float* value  = (const float*)d_in[2];
  const float* mask_u = (const float*)d_in[3];
  const float* Wq = (const float*)d_in[4];
  const float* bq = (const float*)d_in[5];
  const float* Wk = (const float*)d_in[6];
  const float* bk = (const float*)d_in[7];
  const float* Wv = (const float*)d_in[8];
  const float* bv = (const float*)d_in[9];
  const float* Wo = (const float*)d_in[10];
  const float* bo = (const float*)d_in[11];

  char* ws = (char*)d_ws;
  u16* q_bf   = (u16*)(ws + 0);                              // 64MB
  u16* WqT    = (u16*)(ws + ((size_t)64 << 20));             // 32MB
  u16* key_bf = (u16*)(ws + ((size_t)96 << 20));             // 1MB
  u16* val_bf = (u16*)(ws + ((size_t)97 << 20));             // 1MB
  u16* WkT    = (u16*)(ws + ((size_t)98 << 20));             // 0.5MB
  u16* WvT    = (u16*)(ws + ((size_t)98 << 20) + (512 << 10));
  u16* WoT    = (u16*)(ws + ((size_t)99 << 20));             // 0.5MB
  u16* Qp     = (u16*)(ws + ((size_t)100 << 20));            // 64MB
  u16* Kp     = (u16*)(ws + ((size_t)164 << 20));            // 64MB
  u16* Vp     = (u16*)(ws + ((size_t)228 << 20));            // 64MB
  u16* OUTb   = q_bf;                    // alias: q_bf dead after Q-proj
  float* part = (float*)Kp;              // alias: Kp dead after attn (16MB used)

  // casts
  cast_kernel<<<16384, 256, 0, stream>>>(query, q_bf, 8192 * 4096 / 8);
  cast_kernel<<<256, 256, 0, stream>>>(key_in, key_bf, 8192 * 64 / 8);
  cast_kernel<<<256, 256, 0, stream>>>(value, val_bf, 8192 * 64 / 8);
  // B^T panels
  transpose_cast<<<dim3(64, 64), 256, 0, stream>>>(Wq, WqT, 4096, 4096);
  transpose_cast<<<dim3(64, 1), 256, 0, stream>>>(Wk, WkT, 64, 4096);
  transpose_cast<<<dim3(64, 1), 256, 0, stream>>>(Wv, WvT, 64, 4096);
  transpose_cast<<<dim3(1, 64), 256, 0, stream>>>(Wo, WoT, 4096, 64);

  // projections
  gemm_bf16t<128, 128, 2, 2, false, false>
      <<<dim3(32, 64), 256, 0, stream>>>(q_bf, WqT, bq, Qp, 8192, 4096, 4096, 4096, 4096);
  gemm_bf16t<128, 128, 2, 2, false, false>
      <<<dim3(32, 64), 256, 0, stream>>>(key_bf, WkT, bk, Kp, 8192, 4096, 64, 64, 64);
  gemm_bf16t<128, 128, 2, 2, false, false>
      <<<dim3(32, 64), 256, 0, stream>>>(val_bf, WvT, bv, Vp, 8192, 4096, 64, 64, 64);

  // fused per-token attention (MFMA): logits -> log_softmax -> dropout -> @ vT
  attn_mfma<<<2048, 256, 0, stream>>>(Qp, Kp, Vp, mask_u, OUTb);

  // final projection: split-K (8 x 512) partials + reduce -> d_out (f32)
  gemm_bf16t<128, 64, 4, 1, true, true>
      <<<dim3(8, 64), 256, 0, stream>>>(OUTb, WoT, nullptr, part, 8192, 64, 512, 4096, 4096);
  reduce_splitk<<<2048, 256, 0, stream>>>(part, bo, (float*)d_out, 8192 * 64);
}

// Round 6
// 708.793 us; speedup vs baseline: 1.4562x; 1.2213x over previous
//
#include <hip/hip_runtime.h>
#include <stdint.h>
#include <stddef.h>

typedef unsigned short u16;
typedef __bf16 bf16x8 __attribute__((ext_vector_type(8)));
typedef float f32x4 __attribute__((ext_vector_type(4)));

#define DEVINL __device__ __forceinline__

DEVINL u16 f2bf(float f) {
  uint32_t u = __builtin_bit_cast(uint32_t, f);
  u += 0x7FFFu + ((u >> 16) & 1u);   // RNE (finite values only here)
  return (u16)(u >> 16);
}
DEVINL float bf2f(u16 h) {
  uint32_t u = ((uint32_t)h) << 16;
  return __builtin_bit_cast(float, u);
}
DEVINL uint32_t pack2(float a, float b) {
  return (uint32_t)f2bf(a) | ((uint32_t)f2bf(b) << 16);
}

DEVINL void gload_lds16(const u16* g, u16* lds) {
  __builtin_amdgcn_global_load_lds(
      (const __attribute__((address_space(1))) uint32_t*)g,
      (__attribute__((address_space(3))) uint32_t*)lds, 16, 0, 0);
}

// ---------------- cast f32 -> bf16, 8 elem/thread ----------------
__global__ __launch_bounds__(256) void cast_kernel(const float* __restrict__ x,
                                                   u16* __restrict__ y, int n8) {
  int i = blockIdx.x * 256 + threadIdx.x;
  if (i >= n8) return;
  const float4* xp = (const float4*)x + (size_t)i * 2;
  float4 a = xp[0], b = xp[1];
  uint4 o;
  o.x = pack2(a.x, a.y);
  o.y = pack2(a.z, a.w);
  o.z = pack2(b.x, b.y);
  o.w = pack2(b.z, b.w);
  ((uint4*)y)[i] = o;
}

// ------------- transpose + cast: Bt[n][k] = W[k][n] (bf16) -------------
__global__ __launch_bounds__(256) void transpose_cast(const float* __restrict__ W,
                                                      u16* __restrict__ Bt,
                                                      int K, int N) {
  __shared__ float tile[64][65];
  const int nb = blockIdx.x << 6, kb = blockIdx.y << 6;
  const int t = threadIdx.x;
  {
    const int kr = t >> 2, n0 = (t & 3) << 4;
    const float* src = W + (size_t)(kb + kr) * N + nb + n0;
#pragma unroll
    for (int i = 0; i < 16; i += 4) {
      float4 v = *(const float4*)(src + i);
      tile[n0 + i + 0][kr] = v.x;
      tile[n0 + i + 1][kr] = v.y;
      tile[n0 + i + 2][kr] = v.z;
      tile[n0 + i + 3][kr] = v.w;
    }
  }
  __syncthreads();
  {
    const int nr = t >> 2, k0 = (t & 3) << 4;
    u16* dst = Bt + (size_t)(nb + nr) * K + kb + k0;
#pragma unroll
    for (int i = 0; i < 16; i += 8) {
      uint4 o;
      o.x = pack2(tile[nr][k0 + i + 0], tile[nr][k0 + i + 1]);
      o.y = pack2(tile[nr][k0 + i + 2], tile[nr][k0 + i + 3]);
      o.z = pack2(tile[nr][k0 + i + 4], tile[nr][k0 + i + 5]);
      o.w = pack2(tile[nr][k0 + i + 6], tile[nr][k0 + i + 7]);
      *(uint4*)(dst + i) = o;
    }
  }
}

// ------------- m97-style bf16 MFMA GEMM (small/odd shapes; no swizzle) -------------
template <int BM, int BN, int WM, int WN, bool OUTF32, bool SPLITK>
__global__ __launch_bounds__(256) void gemm_bf16t(const u16* __restrict__ A,
                                                  const u16* __restrict__ Bt,
                                                  const float* __restrict__ bias,
                                                  void* __restrict__ Cv,
                                                  int M, int N, int K,
                                                  int lda, int ldb) {
  static_assert(WM * WN == 4, "4 waves");
  constexpr int BK = 32;
  constexpr int FM = BM / (WM * 16);
  constexpr int FN = BN / (WN * 16);
  __shared__ __align__(16) u16 Al[BM * BK];
  __shared__ __align__(16) u16 Bl[BN * BK];
  const int t = threadIdx.x;
  const int lane = t & 63, w = t >> 6;
  const int wm = w / WN, wn = w % WN;

  int bn;
  float* Cpart = nullptr;
  if (SPLITK) {
    const int chunk = blockIdx.x;
    A  += (size_t)chunk * K;      // k-offset within row
    Bt += (size_t)chunk * K;
    Cpart = (float*)Cv + (size_t)chunk * M * N;
    bn = 0;
  } else {
    bn = blockIdx.x * BN;
  }
  const int bm = blockIdx.y * BM;
  const int r16 = lane & 15, khi = lane >> 4;

  f32x4 acc[FM][FN] = {};

  const int srow = t >> 2;           // staging row within a 64-row round
  const int skel = (t & 3) << 3;     // staging k-offset (elements)

  for (int k0 = 0; k0 < K; k0 += BK) {
#pragma unroll
    for (int r = 0; r < BM / 64; ++r) {
      const u16* g = A + (size_t)(bm + r * 64 + srow) * lda + k0 + skel;
      gload_lds16(g, Al + r * 2048 + (w << 9));
    }
#pragma unroll
    for (int r = 0; r < BN / 64; ++r) {
      const u16* g = Bt + (size_t)(bn + r * 64 + srow) * ldb + k0 + skel;
      gload_lds16(g, Bl + r * 2048 + (w << 9));
    }
    __syncthreads();

    bf16x8 af[FM], bfr[FN];
#pragma unroll
    for (int mi = 0; mi < FM; ++mi)
      af[mi] = *(const bf16x8*)(Al + (wm * FM * 16 + mi * 16 + r16) * BK + khi * 8);
#pragma unroll
    for (int ni = 0; ni < FN; ++ni)
      bfr[ni] = *(const bf16x8*)(Bl + (wn * FN * 16 + ni * 16 + r16) * BK + khi * 8);
#pragma unroll
    for (int mi = 0; mi < FM; ++mi)
#pragma unroll
      for (int ni = 0; ni < FN; ++ni)
        acc[mi][ni] = __builtin_amdgcn_mfma_f32_16x16x32_bf16(af[mi], bfr[ni],
                                                              acc[mi][ni], 0, 0, 0);
    __syncthreads();
  }

  // epilogue: C/D layout col = lane&15, row = (lane>>4)*4 + e  [HW-verified r3]
  const int crow0 = bm + wm * FM * 16 + (khi << 2);
  const int ccol0 = bn + wn * FN * 16 + r16;
#pragma unroll
  for (int mi = 0; mi < FM; ++mi) {
#pragma unroll
    for (int ni = 0; ni < FN; ++ni) {
      const int col = ccol0 + ni * 16;
      const float bv = (!SPLITK && bias) ? bias[col] : 0.0f;
#pragma unroll
      for (int e = 0; e < 4; ++e) {
        const int row = crow0 + mi * 16 + e;
        const float v = acc[mi][ni][e] + bv;
        if (SPLITK)
          Cpart[(size_t)row * N + col] = v;
        else if (OUTF32)
          ((float*)Cv)[(size_t)row * N + col] = v;
        else
          ((u16*)Cv)[(size_t)row * N + col] = f2bf(v);
      }
    }
  }
}

// ------------- 256x256 8-phase bf16 GEMM (m201-style, plain HIP) -------------
// C[M][N] = A[M][K] @ Bt[N][K]^T + bias -> bf16. M%256==0, N%256==0, K%64==0,
// nt=K/64 >= 4. 512 threads = 8 waves (2M x 4N); per-wave C = 128x64 with
// M-interleaved 16-row blocks (block 2*mi+wm) so compute-phase q consumes
// exactly A-rows [64q,64q+64).
// LDS 128KB = 2buf x (A 256x64 + B 256x64) bf16. T2 XOR-swizzle
// byte ^= ((row&7)<<4): linear gload_lds dest + pre-swizzled GLOBAL source
// (rule #21) + swizzled ds_read address.
// Issue schedule (r5-audited, shifted): half m=4n+q+5 at tile n phase q ->
// q=0..2 issues target the idle buffer (reads >=2 barriers stale); q=3's
// issue (A half0 of tile n+2, rows 0-127 of the read buffer) overwrites rows
// whose ds_reads all completed before q=1's lgkmcnt(0), two barriers prior.
// Boundary vmcnt(2) keeps 1 half (2 loads) in flight (never 0 mid-loop);
// vmcnt(0) only at the last two boundaries (tail: B half1 of the final tile
// is issued at tile nt-2 q=2 and MUST land before tile nt-1 q=0).
__global__ __launch_bounds__(512, 2) void gemm256(const u16* __restrict__ A,
                                                  const u16* __restrict__ Bt,
                                                  const float* __restrict__ bias,
                                                  u16* __restrict__ C,
                                                  int M, int N, int K) {
  __shared__ __align__(16) u16 LDSu[65536];  // 128 KB
  const int t = threadIdx.x;
  const int lane = t & 63, w = t >> 6;
  const int wm = w >> 2, wn = w & 3;
  const int r16 = lane & 15, khi = lane >> 4;
  const int bm = blockIdx.y << 8, bn = blockIdx.x << 8;
  const int nt = K >> 6;

  // staging geometry (per thread): all 4 rows a thread stages share row&7 ==
  // (t>>3)&7, so one pre-swizzled source chunk works for all of them.
  const int srow = t >> 3;
  const int scb = ((((t & 7) << 4) ^ (((t >> 3) & 7) << 4)) >> 1);  // elements

  auto ISSUE_HALF = [&](int m_) {
    const int tile_ = m_ >> 2, h_ = m_ & 3;
    const int k0_ = tile_ << 6;
    u16* lb_ = LDSu + ((tile_ & 1) << 15) + ((h_ & 2) << 13) + ((h_ & 1) << 13)
               + t * 8;
    const int row0_ = ((h_ & 1) << 7) + srow;
    if (h_ < 2) {
      gload_lds16(A + (size_t)(bm + row0_) * K + k0_ + scb, lb_);
      gload_lds16(A + (size_t)(bm + row0_ + 64) * K + k0_ + scb, lb_ + 4096);
    } else {
      gload_lds16(Bt + (size_t)(bn + row0_) * K + k0_ + scb, lb_);
      gload_lds16(Bt + (size_t)(bn + row0_ + 64) * K + k0_ + scb, lb_ + 4096);
    }
  };

  f32x4 acc[8][4] = {};
  bf16x8 bf[4][2];

  // prologue: stage T0 (4 halves) + T1 A-half0 = 10 loads; allow last half fly.
  for (int m = 0; m < 5; ++m) ISSUE_HALF(m);
  asm volatile("s_waitcnt vmcnt(2)" ::: "memory");
  __builtin_amdgcn_s_barrier();

  for (int n = 0; n < nt; ++n) {
    const u16* bufb = LDSu + ((n & 1) << 15);
#pragma unroll
    for (int q = 0; q < 4; ++q) {
      bf16x8 af[2][2];
      if (q == 0) {
#pragma unroll
        for (int ni = 0; ni < 4; ++ni)
#pragma unroll
          for (int ks = 0; ks < 2; ++ks)
            bf[ni][ks] = *(const bf16x8*)(bufb + 16384 +
                (64 * wn + 16 * ni + r16) * 64 +
                ((((ks << 6) + (khi << 4)) ^ ((r16 & 7) << 4)) >> 1));
      }
#pragma unroll
      for (int mi2 = 0; mi2 < 2; ++mi2)
#pragma unroll
        for (int ks = 0; ks < 2; ++ks)
          af[mi2][ks] = *(const bf16x8*)(bufb +
              (32 * (2 * q + mi2) + 16 * wm + r16) * 64 +
              ((((ks << 6) + (khi << 4)) ^ ((r16 & 7) << 4)) >> 1));
      __builtin_amdgcn_sched_barrier(0);
      {
        const int m = 4 * n + q + 5;
        if (m < 4 * nt) ISSUE_HALF(m);
      }
      __builtin_amdgcn_sched_barrier(0);
      __builtin_amdgcn_s_barrier();
      asm volatile("s_waitcnt lgkmcnt(0)" ::: "memory");
      __builtin_amdgcn_sched_barrier(0);
      __builtin_amdgcn_s_setprio(1);
#pragma unroll
      for (int mi2 = 0; mi2 < 2; ++mi2)
#pragma unroll
        for (int ni = 0; ni < 4; ++ni)
#pragma unroll
          for (int ks = 0; ks < 2; ++ks)
            acc[2 * q + mi2][ni] = __builtin_amdgcn_mfma_f32_16x16x32_bf16(
                af[mi2][ks], bf[ni][ks], acc[2 * q + mi2][ni], 0, 0, 0);
      __builtin_amdgcn_s_setprio(0);
      __builtin_amdgcn_sched_barrier(0);
      if (q == 3) {
        if (n < nt - 2)
          asm volatile("s_waitcnt vmcnt(2)" ::: "memory");
        else
          asm volatile("s_waitcnt vmcnt(0)" ::: "memory");
      }
      __builtin_amdgcn_s_barrier();
    }
  }

  // epilogue: C row = bm + (2mi+wm)*16 + 4khi+e, col = bn + 64wn + 16ni + r16
#pragma unroll
  for (int mi = 0; mi < 8; ++mi) {
    const int row = bm + 32 * mi + 16 * wm + (khi << 2);
#pragma unroll
    for (int ni = 0; ni < 4; ++ni) {
      const int col = bn + 64 * wn + 16 * ni + r16;
      const float bv = bias[col];
#pragma unroll
      for (int e = 0; e < 4; ++e)
        C[(size_t)(row + e) * N + col] = f2bf(acc[mi][ni][e] + bv);
    }
  }
}

// ------------- split-K reduce: out[i] = sum_c part[c][i] + bias[i%64] -------------
__global__ __launch_bounds__(256) void reduce_splitk(const float* __restrict__ part,
                                                     const float* __restrict__ bo,
                                                     float* __restrict__ out, int n) {
  int i = blockIdx.x * 256 + threadIdx.x;
  if (i >= n) return;
  float s = 0.0f;
#pragma unroll
  for (int c = 0; c < 8; ++c) s += part[(size_t)c * 524288 + i];
  out[i] = s + bo[i & 63];
}

// ------------- MFMA per-token attention -------------
__global__ __launch_bounds__(256) void attn_mfma(const u16* __restrict__ Q,
                                                 const u16* __restrict__ Kp,
                                                 const u16* __restrict__ Vp,
                                                 const float* __restrict__ mask,
                                                 u16* __restrict__ OUT) {
  constexpr int LDP = 72;  // u16 row stride (144B, 16B-aligned rows)
  __shared__ __align__(16) u16 Pbuf[4][64 * LDP];  // 36864 B
  const int t = threadIdx.x;
  const int w = t >> 6, lane = t & 63;
  const int r16 = lane & 15, khi = lane >> 4;
  const int s = blockIdx.x * 4 + w;
  const size_t base = (size_t)s << 12;  // * 4096
  u16* pb = Pbuf[w];

  // ---- stage qT: lane loads Qp[s] row m=lane (128B), scatters transposed ----
  {
    uint4 rowv[8];
    const uint4* qp = (const uint4*)(Q + base + (size_t)lane * 64);
#pragma unroll
    for (int i = 0; i < 8; ++i) rowv[i] = qp[i];
#pragma unroll
    for (int i = 0; i < 8; ++i) {
      const uint32_t* wp = (const uint32_t*)&rowv[i];
#pragma unroll
      for (int h = 0; h < 4; ++h) {
        uint32_t v = wp[h];
        pb[(8 * i + 2 * h) * LDP + lane] = (u16)(v & 0xffffu);
        pb[(8 * i + 2 * h + 1) * LDP + lane] = (u16)(v >> 16);
      }
    }
  }
  asm volatile("s_waitcnt lgkmcnt(0)" ::: "memory");  // cross-lane LDS RAW fence

  // ---- QK^T via MFMA ----
  f32x4 acc[4][4] = {};
#pragma unroll
  for (int ks = 0; ks < 2; ++ks) {
    bf16x8 af[4], bfr[4];
#pragma unroll
    for (int mi = 0; mi < 4; ++mi)
      af[mi] = *(const bf16x8*)(pb + (16 * mi + r16) * LDP + ks * 32 + khi * 8);
#pragma unroll
    for (int ni = 0; ni < 4; ++ni)
      bfr[ni] = *(const bf16x8*)(Kp + base + (size_t)(16 * ni + r16) * 64 +
                                 ks * 32 + khi * 8);
#pragma unroll
    for (int mi = 0; mi < 4; ++mi)
#pragma unroll
      for (int ni = 0; ni < 4; ++ni)
        acc[mi][ni] = __builtin_amdgcn_mfma_f32_16x16x32_bf16(af[mi], bfr[ni],
                                                              acc[mi][ni], 0, 0, 0);
  }

  // ---- log-softmax over cols: reduce over ni (regs) + r16 (shfl_xor) ----
  float L[4][4];
#pragma unroll
  for (int mi = 0; mi < 4; ++mi) {
#pragma unroll
    for (int e = 0; e < 4; ++e) {
      float mx = fmaxf(fmaxf(acc[mi][0][e], acc[mi][1][e]),
                       fmaxf(acc[mi][2][e], acc[mi][3][e]));
      mx = fmaxf(mx, __shfl_xor(mx, 1));
      mx = fmaxf(mx, __shfl_xor(mx, 2));
      mx = fmaxf(mx, __shfl_xor(mx, 4));
      mx = fmaxf(mx, __shfl_xor(mx, 8));
      float sm = __expf(acc[mi][0][e] - mx) + __expf(acc[mi][1][e] - mx) +
                 __expf(acc[mi][2][e] - mx) + __expf(acc[mi][3][e] - mx);
      sm += __shfl_xor(sm, 1);
      sm += __shfl_xor(sm, 2);
      sm += __shfl_xor(sm, 4);
      sm += __shfl_xor(sm, 8);
      L[mi][e] = mx + __logf(sm);
    }
  }

  // ---- P = (logits - L) * keep -> bf16 into pb ----
  const float* mrow = mask + base;
#pragma unroll
  for (int mi = 0; mi < 4; ++mi) {
#pragma unroll
    for (int ni = 0; ni < 4; ++ni) {
#pragma unroll
      for (int e = 0; e < 4; ++e) {
        const int c = 16 * mi + 4 * khi + e;
        const int j = 16 * ni + r16;
        const float keep = mrow[(size_t)c * 64 + j] > 0.25f ? (1.0f / 0.75f) : 0.0f;
        pb[c * LDP + j] = f2bf((acc[mi][ni][e] - L[mi][e]) * keep);
      }
    }
  }
  asm volatile("s_waitcnt lgkmcnt(0)" ::: "memory");  // cross-lane LDS RAW fence

  // ---- PV via MFMA ----
  f32x4 o[4][4] = {};
#pragma unroll
  for (int ks = 0; ks < 2; ++ks) {
    bf16x8 af[4], bfr[4];
#pragma unroll
    for (int mi = 0; mi < 4; ++mi)
      af[mi] = *(const bf16x8*)(pb + (16 * mi + r16) * LDP + ks * 32 + khi * 8);
#pragma unroll
    for (int ni = 0; ni < 4; ++ni)
      bfr[ni] = *(const bf16x8*)(Vp + base + (size_t)(16 * ni + r16) * 64 +
                                 ks * 32 + khi * 8);
#pragma unroll
    for (int mi = 0; mi < 4; ++mi)
#pragma unroll
      for (int ni = 0; ni < 4; ++ni)
        o[mi][ni] = __builtin_amdgcn_mfma_f32_16x16x32_bf16(af[mi], bfr[ni],
                                                            o[mi][ni], 0, 0, 0);
  }

  // ---- store OUT[s][c*64+jo] bf16 ----
#pragma unroll
  for (int mi = 0; mi < 4; ++mi) {
#pragma unroll
    for (int ni = 0; ni < 4; ++ni) {
#pragma unroll
      for (int e = 0; e < 4; ++e) {
        const int c = 16 * mi + 4 * khi + e;
        const int jo = 16 * ni + r16;
        OUT[base + (size_t)c * 64 + jo] = f2bf(o[mi][ni][e]);
      }
    }
  }
}

// ---------------- launch ----------------
extern "C" void kernel_launch(void* const* d_in, const int* in_sizes, int n_in,
                              void* d_out, int out_size, void* d_ws, size_t ws_size,
                              hipStream_t stream) {
  (void)in_sizes; (void)n_in; (void)out_size; (void)ws_size;
  const float* query  = (const float*)d_in[0];
  const float* key_in = (const float*)d_in[1];
  const float* value  = (const float*)d_in[2];
  const float* mask_u = (const float*)d_in[3];
  const float* Wq = (const float*)d_in[4];
  const float* bq = (const float*)d_in[5];
  const float* Wk = (const float*)d_in[6];
  const float* bk = (const float*)d_in[7];
  const float* Wv = (const float*)d_in[8];
  const float* bv = (const float*)d_in[9];
  const float* Wo = (const float*)d_in[10];
  const float* bo = (const float*)d_in[11];

  char* ws = (char*)d_ws;
  u16* q_bf   = (u16*)(ws + 0);                              // 64MB
  u16* WqT    = (u16*)(ws + ((size_t)64 << 20));             // 32MB
  u16* key_bf = (u16*)(ws + ((size_t)96 << 20));             // 1MB
  u16* val_bf = (u16*)(ws + ((size_t)97 << 20));             // 1MB
  u16* WkT    = (u16*)(ws + ((size_t)98 << 20));             // 0.5MB
  u16* WvT    = (u16*)(ws + ((size_t)98 << 20) + (512 << 10));
  u16* WoT    = (u16*)(ws + ((size_t)99 << 20));             // 0.5MB
  u16* Qp     = (u16*)(ws + ((size_t)100 << 20));            // 64MB
  u16* Kp     = (u16*)(ws + ((size_t)164 << 20));            // 64MB
  u16* Vp     = (u16*)(ws + ((size_t)228 << 20));            // 64MB
  u16* OUTb   = q_bf;                    // alias: q_bf dead after Q-proj
  float* part = (float*)Kp;              // alias: Kp dead after attn (16MB used)

  // casts
  cast_kernel<<<16384, 256, 0, stream>>>(query, q_bf, 8192 * 4096 / 8);
  cast_kernel<<<256, 256, 0, stream>>>(key_in, key_bf, 8192 * 64 / 8);
  cast_kernel<<<256, 256, 0, stream>>>(value, val_bf, 8192 * 64 / 8);
  // B^T panels
  transpose_cast<<<dim3(64, 64), 256, 0, stream>>>(Wq, WqT, 4096, 4096);
  transpose_cast<<<dim3(64, 1), 256, 0, stream>>>(Wk, WkT, 64, 4096);
  transpose_cast<<<dim3(64, 1), 256, 0, stream>>>(Wv, WvT, 64, 4096);
  transpose_cast<<<dim3(1, 64), 256, 0, stream>>>(Wo, WoT, 4096, 64);

  // Q projection: 8-phase 256^2 kernel (M=8192, N=4096, K=4096)
  gemm256<<<dim3(16, 32), 512, 0, stream>>>(q_bf, WqT, bq, Qp, 8192, 4096, 4096);
  // K/V projections: m97 structure (K=64 too small for 8-phase)
  gemm_bf16t<128, 128, 2, 2, false, false>
      <<<dim3(32, 64), 256, 0, stream>>>(key_bf, WkT, bk, Kp, 8192, 4096, 64, 64, 64);
  gemm_bf16t<128, 128, 2, 2, false, false>
      <<<dim3(32, 64), 256, 0, stream>>>(val_bf, WvT, bv, Vp, 8192, 4096, 64, 64, 64);

  // fused per-token attention (MFMA): logits -> log_softmax -> dropout -> @ vT
  attn_mfma<<<2048, 256, 0, stream>>>(Qp, Kp, Vp, mask_u, OUTb);

  // final projection: split-K (8 x 512) partials + reduce -> d_out (f32)
  gemm_bf16t<128, 64, 4, 1, true, true>
      <<<dim3(8, 64), 256, 0, stream>>>(OUTb, WoT, nullptr, part, 8192, 64, 512, 4096, 4096);
  reduce_splitk<<<2048, 256, 0, stream>>>(part, bo, (float*)d_out, 8192 * 64);
}